// Round 1
// baseline (341.230 us; speedup 1.0000x reference)
//
#include <hip/hip_runtime.h>
#include <hip/hip_bf16.h>

// Problem: B=2048, P=50, C=512, H=7, W=8  ->  M=2048, N=50 (pad 64), K=28672
//   out[b,p] = relu( sum_k x[b,k]^2 + sum_k p[p,k]^2 - 2 * sum_k x[b,k]*p[p,k] )
//
// Strategy: bf16 MFMA NT-GEMM (threshold is 2% abs -> bf16 products are fine),
// fused fp32 x^2 accumulation during the x streaming pass. Memory-bound:
// 235 MB of x read once at ~6 TB/s.

typedef __bf16 bf16_t;
typedef bf16_t bf16x8 __attribute__((ext_vector_type(8)));
typedef bf16_t bf16x4 __attribute__((ext_vector_type(4)));
typedef float  floatx4 __attribute__((ext_vector_type(4)));

#define KDIM 28672
#define BDIM 2048
#define KSPLIT 16
#define KCHUNK (KDIM / KSPLIT)   // 1792
#define ITERS (KCHUNK / 64)      // 28
#define LDS_STRIDE 72            // 64 + 8 pad: keeps 16B alignment, breaks bank pileups

// ---------------- kernel 1: prototype -> bf16 [64][K], p2[p] ----------------
__global__ __launch_bounds__(256) void proto_prep(const float* __restrict__ proto,
                                                  bf16_t* __restrict__ pb,
                                                  float* __restrict__ p2) {
    int p = blockIdx.x;   // 0..63
    int t = threadIdx.x;  // 0..255
    float acc = 0.f;
    if (p < 50) {
        const floatx4* src = (const floatx4*)(proto + (long)p * KDIM);
        for (int i = t; i < KDIM / 4; i += 256) {
            floatx4 v = src[i];
            acc += v[0]*v[0] + v[1]*v[1] + v[2]*v[2] + v[3]*v[3];
            bf16x4 o;
            o[0] = (bf16_t)v[0]; o[1] = (bf16_t)v[1];
            o[2] = (bf16_t)v[2]; o[3] = (bf16_t)v[3];
            *(bf16x4*)(pb + (long)p * KDIM + i * 4) = o;
        }
    } else {
        bf16x4 z;
        z[0] = (bf16_t)0.f; z[1] = (bf16_t)0.f; z[2] = (bf16_t)0.f; z[3] = (bf16_t)0.f;
        for (int i = t; i < KDIM / 4; i += 256)
            *(bf16x4*)(pb + (long)p * KDIM + i * 4) = z;
    }
    __shared__ float sred[256];
    sred[t] = acc;
    __syncthreads();
    for (int s = 128; s > 0; s >>= 1) {
        if (t < s) sred[t] += sred[t + s];
        __syncthreads();
    }
    if (t == 0) p2[p] = (p < 50) ? sred[0] : 0.f;
}

// ---------------- kernel 2: main fused GEMM + x2 ----------------
// grid (32, 16): blockIdx.x = M-tile (64 rows), blockIdx.y = K-split
__global__ __launch_bounds__(256, 2) void proto_main(const float* __restrict__ x,
                                                     const bf16_t* __restrict__ pb,
                                                     float* __restrict__ xpp,
                                                     float* __restrict__ x2p) {
    __shared__ bf16_t As[64 * LDS_STRIDE];
    __shared__ bf16_t Bs[64 * LDS_STRIDE];

    const int t = threadIdx.x;
    const int mbase = blockIdx.x * 64;
    const int ks = blockIdx.y;
    const int kbase0 = ks * KCHUNK;

    // staging role: 4 threads per row, 16 consecutive floats each
    const int row = t >> 2;
    const int q = t & 3;
    const float* xrow = x + (long)(mbase + row) * KDIM + kbase0 + q * 16;
    const bf16_t* prow = pb + (long)row * KDIM + kbase0 + q * 16;
    bf16_t* aw = As + row * LDS_STRIDE + q * 16;
    bf16_t* bw = Bs + row * LDS_STRIDE + q * 16;

    // compute role: 4 waves in 2x2 over the 64x64 tile, each wave 32x32
    const int lane = t & 63;
    const int wave = t >> 6;
    const int m0 = (wave >> 1) * 32;
    const int n0 = (wave & 1) * 32;
    const int lr = lane & 15;
    const int lk = (lane >> 4) * 8;   // k offset within 32-wide MFMA K

    floatx4 acc00 = {0.f, 0.f, 0.f, 0.f};
    floatx4 acc01 = {0.f, 0.f, 0.f, 0.f};
    floatx4 acc10 = {0.f, 0.f, 0.f, 0.f};
    floatx4 acc11 = {0.f, 0.f, 0.f, 0.f};
    float x2acc = 0.f;

    for (int it = 0; it < ITERS; ++it) {
        const int kb = it * 64;
        // global loads (issued before the barrier -> in flight during prior compute)
        floatx4 v0 = *(const floatx4*)(xrow + kb);
        floatx4 v1 = *(const floatx4*)(xrow + kb + 4);
        floatx4 v2 = *(const floatx4*)(xrow + kb + 8);
        floatx4 v3 = *(const floatx4*)(xrow + kb + 12);
        bf16x8 pv0 = ((const bf16x8*)(prow + kb))[0];
        bf16x8 pv1 = ((const bf16x8*)(prow + kb))[1];

        // fused x^2 (fp32) + convert to bf16
        x2acc += v0[0]*v0[0] + v0[1]*v0[1] + v0[2]*v0[2] + v0[3]*v0[3]
               + v1[0]*v1[0] + v1[1]*v1[1] + v1[2]*v1[2] + v1[3]*v1[3]
               + v2[0]*v2[0] + v2[1]*v2[1] + v2[2]*v2[2] + v2[3]*v2[3]
               + v3[0]*v3[0] + v3[1]*v3[1] + v3[2]*v3[2] + v3[3]*v3[3];
        bf16x8 lo, hi;
        lo[0] = (bf16_t)v0[0]; lo[1] = (bf16_t)v0[1]; lo[2] = (bf16_t)v0[2]; lo[3] = (bf16_t)v0[3];
        lo[4] = (bf16_t)v1[0]; lo[5] = (bf16_t)v1[1]; lo[6] = (bf16_t)v1[2]; lo[7] = (bf16_t)v1[3];
        hi[0] = (bf16_t)v2[0]; hi[1] = (bf16_t)v2[1]; hi[2] = (bf16_t)v2[2]; hi[3] = (bf16_t)v2[3];
        hi[4] = (bf16_t)v3[0]; hi[5] = (bf16_t)v3[1]; hi[6] = (bf16_t)v3[2]; hi[7] = (bf16_t)v3[3];

        __syncthreads();   // prior iter's LDS reads done
        *(bf16x8*)aw       = lo;
        *(bf16x8*)(aw + 8) = hi;
        *(bf16x8*)bw       = pv0;
        *(bf16x8*)(bw + 8) = pv1;
        __syncthreads();   // tile visible

        #pragma unroll
        for (int kk = 0; kk < 64; kk += 32) {
            bf16x8 a0 = *(const bf16x8*)(As + (m0 + lr) * LDS_STRIDE + kk + lk);
            bf16x8 a1 = *(const bf16x8*)(As + (m0 + 16 + lr) * LDS_STRIDE + kk + lk);
            bf16x8 b0 = *(const bf16x8*)(Bs + (n0 + lr) * LDS_STRIDE + kk + lk);
            bf16x8 b1 = *(const bf16x8*)(Bs + (n0 + 16 + lr) * LDS_STRIDE + kk + lk);
            acc00 = __builtin_amdgcn_mfma_f32_16x16x32_bf16(a0, b0, acc00, 0, 0, 0);
            acc01 = __builtin_amdgcn_mfma_f32_16x16x32_bf16(a0, b1, acc01, 0, 0, 0);
            acc10 = __builtin_amdgcn_mfma_f32_16x16x32_bf16(a1, b0, acc10, 0, 0, 0);
            acc11 = __builtin_amdgcn_mfma_f32_16x16x32_bf16(a1, b1, acc11, 0, 0, 0);
        }
    }

    // write xp partials: C/D layout col = lane&15, row = (lane>>4)*4 + reg
    const long base = ((long)ks * BDIM + mbase) * 64;
    const int nn = lane & 15;
    #pragma unroll
    for (int r = 0; r < 4; ++r) {
        const int ml = m0 + (lane >> 4) * 4 + r;
        xpp[base + (long)ml * 64 + n0 + nn]             = acc00[r];
        xpp[base + (long)ml * 64 + n0 + 16 + nn]        = acc01[r];
        xpp[base + (long)(ml + 16) * 64 + n0 + nn]      = acc10[r];
        xpp[base + (long)(ml + 16) * 64 + n0 + 16 + nn] = acc11[r];
    }

    // x2 partial: 4 staging threads per row -> reduce via LDS (reuse As)
    __syncthreads();
    float* red = (float*)As;
    red[t] = x2acc;
    __syncthreads();
    if (t < 64) {
        float s = red[4 * t] + red[4 * t + 1] + red[4 * t + 2] + red[4 * t + 3];
        x2p[ks * BDIM + mbase + t] = s;
    }
}

// ---------------- kernel 3: reduce split-K + epilogue ----------------
__global__ __launch_bounds__(256) void proto_finalize(const float* __restrict__ xpp,
                                                      const float* __restrict__ x2p,
                                                      const float* __restrict__ p2,
                                                      float* __restrict__ out) {
    int idx = blockIdx.x * 256 + threadIdx.x;  // 0 .. 2048*64-1
    int b = idx >> 6;
    int n = idx & 63;
    if (n >= 50) return;
    float xp = 0.f, x2 = 0.f;
    #pragma unroll
    for (int ksi = 0; ksi < KSPLIT; ++ksi) {
        xp += xpp[((long)ksi * BDIM + b) * 64 + n];
        x2 += x2p[ksi * BDIM + b];
    }
    float d = x2 + p2[n] - 2.f * xp;
    out[b * 50 + n] = d > 0.f ? d : 0.f;
}

// ---------------- launch ----------------
extern "C" void kernel_launch(void* const* d_in, const int* in_sizes, int n_in,
                              void* d_out, int out_size, void* d_ws, size_t ws_size,
                              hipStream_t stream) {
    const float* x = (const float*)d_in[0];
    const float* proto = (const float*)d_in[1];
    float* out = (float*)d_out;

    char* ws = (char*)d_ws;
    // ws layout (bytes, 256-aligned):
    //   [0)                proto_bf16: 64*28672*2 = 3,670,016
    //   [3,670,016)        p2:         64*4       = 256
    //   [3,670,272)        x2p:        16*2048*4  = 131,072
    //   [3,801,344)        xpp:        16*2048*64*4 = 8,388,608   (total ~11.6 MB)
    bf16_t* pb  = (bf16_t*)(ws);
    float*  p2  = (float*)(ws + 3670016);
    float*  x2p = (float*)(ws + 3670272);
    float*  xpp = (float*)(ws + 3801344);

    proto_prep<<<64, 256, 0, stream>>>(proto, pb, p2);
    proto_main<<<dim3(32, KSPLIT), 256, 0, stream>>>(x, pb, xpp, x2p);
    proto_finalize<<<(BDIM * 64) / 256, 256, 0, stream>>>(xpp, x2p, p2, out);
}